// Round 10
// baseline (21815.097 us; speedup 1.0000x reference)
//
#include <hip/hip_runtime.h>
#include <hip/hip_bf16.h>

// TGCN: B=64, T=500, N=21, HID=128.
// Round 10 (base = round 7, the 12.5ms best): the 5 per-step broadcast passes
// (ds_read_b128 x 3840/CU ~= 46K cyc) are the measured bottleneck, and all are
// WAVE-PRIVATE round trips. Move 3 of them (H1-P1, AH, H2) to per-block
// global staging in d_ws, read back as global_load_dwordx4 broadcasts via the
// same-CU L1/L2 (same-wave store->load ordered by compiler vmcnt on the same
// __restrict pointer; cross-tick cases covered by the barrier's vmcnt drain).
// HR1/HR2 stay in LDS. Lane's OWN H1/H2 gate values kept in registers
// (identical values). LDS pipe ~46K -> ~18K cyc; VMEM ~+10K: one saturated
// pipe becomes two half-loaded pipes that 2 waves/SIMD can overlap.
// All accumulation chains BIT-IDENTICAL to round 7. Never reorder fp32 sums.

#define NN 21
#define NROW 24            // padded rows (21,22,23 zero)
#define HID 128
#define TSTEPS 500
#define EDGES 210
#define NTHREADS 512       // 8 waves: 4 per group
#define RPT 6              // rows per thread (within a group)

// ws layout (float offsets)
#define WS_A     0        // NROW*NN floats (pad rows zeroed on build)
#define WS_VEC   1600     // 9*128
#define WS_LZR1  3200     // 32*256*4 floats
#define WS_LH1   36000    // 32*128*4
#define WS_WE2   52400    // 32*384*4
#define WS_LZR2  101600   // 32*256*4
#define WS_LH2   134400   // 32*128*4
// per-block global staging (wave-private broadcast buffers)
#define WS_H1G   150784   // 64 blocks * 2 * 3072 (double-buffered H1)
#define WS_AHG   544000   // 64 * 3072
#define WS_H2G   740608   // 64 * 3072
// total = 937216 floats (~3.75 MB of d_ws)

#define WAVE_SYNC() asm volatile("s_waitcnt lgkmcnt(0)" ::: "memory")

typedef float v2f __attribute__((ext_vector_type(2)));

__device__ __forceinline__ v2f lo2(float4 w) { v2f v = {w.x, w.y}; return v; }
__device__ __forceinline__ v2f hi2(float4 w) { v2f v = {w.z, w.w}; return v; }
__device__ __forceinline__ void pkf(v2f& acc, float s, v2f w) {
    v2f ss = {s, s};
    acc = __builtin_elementwise_fma(ss, w, acc);
}
__device__ __forceinline__ float sigmoidf(float v) {
    return 1.0f / (1.0f + expf(-v));
}

// ---- Prologue: build normalized adjacency A (21x21) in fp64, store fp32 ----
__global__ void build_A(const int* __restrict__ ei, const float* __restrict__ ew,
                        float* __restrict__ Aout) {
    __shared__ double deg[NN];
    __shared__ double dinv[NN];
    __shared__ double Asm[NN * NN];
    int t = threadIdx.x;
    for (int k = t; k < NN * NN; k += blockDim.x) Asm[k] = 0.0;
    if (t < NN) deg[t] = 1.0;  // self loop weight 1
    __syncthreads();
    if (t == 0) {
        for (int e = 0; e < EDGES; e++) deg[ei[EDGES + e]] += (double)ew[e];
        for (int i = 0; i < NN; i++) dinv[i] = deg[i] > 0.0 ? 1.0 / sqrt(deg[i]) : 0.0;
        for (int e = 0; e < EDGES; e++) {
            int s = ei[e], d = ei[EDGES + e];
            Asm[d * NN + s] += dinv[s] * (double)ew[e] * dinv[d];
        }
        for (int i = 0; i < NN; i++) Asm[i * NN + i] += dinv[i] * dinv[i];
    }
    __syncthreads();
    for (int k = t; k < NROW * NN; k += blockDim.x)
        Aout[k] = (k < NN * NN) ? (float)Asm[k] : 0.0f;
}

// ---- Prologue: repack bottom halves of (256,128) concat weights ----------
// Pair-interleaved: float4 idx = c*(ngate*128) + gate*128 + k2*64 + f0,
// k = 4c + 2*k2, contents {w[k][f0], w[k][f0+64], w[k+1][f0], w[k+1][f0+64]}
__global__ void pack_bot(const float* __restrict__ w0, const float* __restrict__ w1,
                         float4* __restrict__ out, int ngate) {
    int t = blockIdx.x * blockDim.x + threadIdx.x;
    int per_c = ngate * 128;
    int total = 32 * per_c;
    if (t >= total) return;
    int c = t / per_c, rem = t - c * per_c;
    int gate = rem >> 7;
    int r2 = rem & 127;
    int k2 = r2 >> 6;
    int f0 = r2 & 63;
    int k = 4 * c + 2 * k2;
    const float* src = (gate == 0) ? w0 : w1;
    float4 v;
    v.x = src[(128 + k) * 128 + f0];
    v.y = src[(128 + k) * 128 + f0 + 64];
    v.z = src[(128 + k + 1) * 128 + f0];
    v.w = src[(128 + k + 1) * 128 + f0 + 64];
    out[t] = v;
}

// ---- Prologue: Weff2_g = Wg_2 @ lgw_2_top, pair-interleaved, fp64 accum ----
__global__ void make_weff2(const float* __restrict__ Wz2, const float* __restrict__ Wr2,
                           const float* __restrict__ Wh2,
                           const float* __restrict__ lzw2, const float* __restrict__ lrw2,
                           const float* __restrict__ lhw2,
                           float4* __restrict__ out) {
    int t = blockIdx.x * blockDim.x + threadIdx.x;  // [0, 32*384)
    if (t >= 32 * 384) return;
    int c = t / 384, rem = t - c * 384;
    int g = rem >> 7;
    int r2 = rem & 127;
    int k2 = r2 >> 6;
    int f0 = r2 & 63;
    int k = 4 * c + 2 * k2;
    const float* W = (g == 0) ? Wz2 : (g == 1) ? Wr2 : Wh2;
    const float* L = (g == 0) ? lzw2 : (g == 1) ? lrw2 : lhw2;
    double a0 = 0, a1 = 0, a2 = 0, a3 = 0;
    for (int m = 0; m < 128; m++) {
        double w0 = (double)W[k * 128 + m];
        double w1 = (double)W[(k + 1) * 128 + m];
        a0 += w0 * (double)L[m * 128 + f0];
        a1 += w0 * (double)L[m * 128 + f0 + 64];
        a2 += w1 * (double)L[m * 128 + f0];
        a3 += w1 * (double)L[m * 128 + f0 + 64];
    }
    out[t] = make_float4((float)a0, (float)a1, (float)a2, (float)a3);
}

// ---- Prologue: layer-1 effective row vectors + all bias consts (fp64) ----
__global__ void make_vecs(const float* __restrict__ Wz1, const float* __restrict__ Wr1,
                          const float* __restrict__ Wh1,
                          const float* __restrict__ bz1, const float* __restrict__ br1,
                          const float* __restrict__ bh1,
                          const float* __restrict__ lzw1, const float* __restrict__ lrw1,
                          const float* __restrict__ lhw1,
                          const float* __restrict__ lzb1, const float* __restrict__ lrb1,
                          const float* __restrict__ lhb1,
                          const float* __restrict__ bz2, const float* __restrict__ br2,
                          const float* __restrict__ bh2,
                          const float* __restrict__ lzw2, const float* __restrict__ lrw2,
                          const float* __restrict__ lhw2,
                          const float* __restrict__ lzb2, const float* __restrict__ lrb2,
                          const float* __restrict__ lhb2,
                          float* __restrict__ out) {
    int t = blockIdx.x * blockDim.x + threadIdx.x;
    if (t >= 9 * 128) return;
    int v = t >> 7, f = t & 127;
    double acc = 0.0;
    if (v < 3) {
        const float* W = (v == 0) ? Wz1 : (v == 1) ? Wr1 : Wh1;   // (1,128)
        const float* L = (v == 0) ? lzw1 : (v == 1) ? lrw1 : lhw1;
        for (int m = 0; m < 128; m++) acc += (double)W[m] * (double)L[m * 128 + f];
    } else if (v < 6) {
        int g = v - 3;
        const float* bb = (g == 0) ? bz1 : (g == 1) ? br1 : bh1;
        const float* L  = (g == 0) ? lzw1 : (g == 1) ? lrw1 : lhw1;
        const float* lb = (g == 0) ? lzb1 : (g == 1) ? lrb1 : lhb1;
        for (int m = 0; m < 128; m++) acc += (double)bb[m] * (double)L[m * 128 + f];
        acc += (double)lb[f];
    } else {
        int g = v - 6;
        const float* bb = (g == 0) ? bz2 : (g == 1) ? br2 : bh2;
        const float* L  = (g == 0) ? lzw2 : (g == 1) ? lrw2 : lhw2;
        const float* lb = (g == 0) ? lzb2 : (g == 1) ? lrb2 : lhb2;
        for (int m = 0; m < 128; m++) acc += (double)bb[m] * (double)L[m * 128 + f];
        acc += (double)lb[f];
    }
    out[t] = (float)acc;
}

// ---- Main: one block per batch, layer-pipelined groups, LDS/VMEM split ----
__global__ __launch_bounds__(NTHREADS, 2) void tgcn_main(
    const float* __restrict__ x,       // (64,500,21)
    const float* __restrict__ ws,
    float* __restrict__ h1g,           // staging: 64 x 2 x 3072
    float* __restrict__ ahg,           // staging: 64 x 3072
    float* __restrict__ h2g,           // staging: 64 x 3072
    const float* __restrict__ cls_w,   // (128,1)
    const float* __restrict__ cls_b,   // (1,)
    float* __restrict__ out)           // (64,)
{
    const int b  = blockIdx.x;
    const int t  = threadIdx.x;
    const bool isA = (t < 256);                              // wave-uniform
    const int lt = t & 255;
    const int f0 = lt & 63;
    const int f1 = f0 + 64;
    const int gw = __builtin_amdgcn_readfirstlane(lt >> 6);  // 0..3 in group
    const int iA = gw * RPT;
    const int nreal = (iA + RPT <= NN) ? RPT : (NN - iA);

    float* h1gb = h1g + (size_t)b * 6144;   // two 3072 buffers
    float* ahgb = ahg + (size_t)b * 3072;
    float* h2gb = h2g + (size_t)b * 3072;

    __shared__ __align__(16) float sH1[2][NROW * HID];  // for cross-wave P3 reads
    __shared__ __align__(16) float sHR1[NROW * HID];
    __shared__ __align__(16) float sHR2[NROW * HID];
    __shared__ float sA[NROW * NN];
    __shared__ float sax[2][NROW];
    __shared__ double sred[4][HID];

    const float*  vecs = ws + WS_VEC;
    const float4* Lzr1 = (const float4*)(ws + WS_LZR1);
    const float4* Lh1  = (const float4*)(ws + WS_LH1);
    const float4* We2  = (const float4*)(ws + WS_WE2);
    const float4* Lzr2 = (const float4*)(ws + WS_LZR2);
    const float4* Lh2  = (const float4*)(ws + WS_LH2);

    const float4* HR1v = (const float4*)sHR1;
    const float4* HR2v = (const float4*)sHR2;

    for (int k = t; k < 2 * NROW * HID; k += NTHREADS) ((float*)sH1)[k] = 0.0f;
    for (int k = t; k < 6144; k += NTHREADS) h1gb[k] = 0.0f;
    for (int k = t; k < 3072; k += NTHREADS) h2gb[k] = 0.0f;
    for (int k = t; k < NROW * NN; k += NTHREADS) sA[k] = ws[WS_A + k];

    // per-column-pair constants
    const v2f wz1v = {vecs[f0],        vecs[f1]};
    const v2f wr1v = {vecs[128 + f0],  vecs[128 + f1]};
    const v2f wh1v = {vecs[256 + f0],  vecs[256 + f1]};
    const v2f cz1v = {vecs[384 + f0],  vecs[384 + f1]};
    const v2f cr1v = {vecs[512 + f0],  vecs[512 + f1]};
    const v2f ch1v = {vecs[640 + f0],  vecs[640 + f1]};
    const v2f cz2v = {vecs[768 + f0],  vecs[768 + f1]};
    const v2f cr2v = {vecs[896 + f0],  vecs[896 + f1]};
    const v2f ch2v = {vecs[1024 + f0], vecs[1024 + f1]};

    __syncthreads();   // also drains the staging zero-stores (vmcnt)

    const float* xb = x + (size_t)b * (TSTEPS * NN);
    if (t < NROW) {  // sax for steps 0 and 1 (slot = s&1)
        float a0s = 0.0f, a1s = 0.0f;
        for (int j = 0; j < NN; j++) {
            a0s = fmaf(sA[t * NN + j], xb[j], a0s);
            a1s = fmaf(sA[t * NN + j], xb[NN + j], a1s);
        }
        sax[0][t] = a0s;
        sax[1][t] = a1s;
    }
    __syncthreads();

    double oacc0 = 0.0, oacc1 = 0.0;   // group B only

    // lane's own state values, kept in registers (identical to LDS reads)
    v2f h1keep[RPT];   // A: H1[iA+r][f0,f1]
    v2f h2keep[RPT];   // B: H2[iA+r][f0,f1]
    #pragma unroll
    for (int r = 0; r < RPT; r++) { h1keep[r] = (v2f){0.f, 0.f}; h2keep[r] = (v2f){0.f, 0.f}; }

    // ============ A-group layer-1 body (step s: read buf (s+1)&1, write s&1) ==
    auto layer1 = [&](int s) {
        const float4* gH1 = (const float4*)(h1gb + ((s + 1) & 1) * 3072);
        float* H1wrL = sH1[s & 1];
        float* H1wrG = h1gb + (s & 1) * 3072;
        float axp[RPT];
        #pragma unroll
        for (int r = 0; r < RPT; r++) axp[r] = sax[s & 1][iA + r];
        // P1: z,r gates — H1 broadcast from GLOBAL staging
        v2f az[RPT], ar[RPT];
        #pragma unroll
        for (int r = 0; r < RPT; r++) {
            az[r] = __builtin_elementwise_fma((v2f){axp[r], axp[r]}, wz1v, cz1v);
            ar[r] = __builtin_elementwise_fma((v2f){axp[r], axp[r]}, wr1v, cr1v);
        }
        for (int c = 0; c < 32; ++c) {
            const float4 wz0 = Lzr1[c * 256 + f0];
            const float4 wz1 = Lzr1[c * 256 + 64 + f0];
            const float4 wr0 = Lzr1[c * 256 + 128 + f0];
            const float4 wr1 = Lzr1[c * 256 + 192 + f0];
            #pragma unroll
            for (int r = 0; r < RPT; r++) {
                const float4 h = gH1[(iA + r) * 32 + c];
                pkf(az[r], h.x, lo2(wz0)); pkf(az[r], h.y, hi2(wz0));
                pkf(az[r], h.z, lo2(wz1)); pkf(az[r], h.w, hi2(wz1));
                pkf(ar[r], h.x, lo2(wr0)); pkf(ar[r], h.y, hi2(wr0));
                pkf(ar[r], h.z, lo2(wr1)); pkf(ar[r], h.w, hi2(wr1));
            }
        }
        v2f zg[RPT], h1c[RPT];
        #pragma unroll
        for (int r = 0; r < RPT; r++) {
            zg[r].x = sigmoidf(az[r].x);
            zg[r].y = sigmoidf(az[r].y);
            const float r0 = sigmoidf(ar[r].x);
            const float r1 = sigmoidf(ar[r].y);
            h1c[r] = h1keep[r];                       // own values, from regs
            sHR1[(iA + r) * HID + f0] = h1c[r].x * r0;
            sHR1[(iA + r) * HID + f1] = h1c[r].y * r1;
        }
        WAVE_SYNC();
        // P2: h gate + H1 update — HR1 via LDS (wave-private)
        v2f ah[RPT];
        #pragma unroll
        for (int r = 0; r < RPT; r++)
            ah[r] = __builtin_elementwise_fma((v2f){axp[r], axp[r]}, wh1v, ch1v);
        for (int c = 0; c < 32; ++c) {
            const float4 wh0 = Lh1[c * 128 + f0];
            const float4 wh1 = Lh1[c * 128 + 64 + f0];
            #pragma unroll
            for (int r = 0; r < RPT; r++) {
                const float4 q = HR1v[(iA + r) * 32 + c];
                pkf(ah[r], q.x, lo2(wh0)); pkf(ah[r], q.y, hi2(wh0));
                pkf(ah[r], q.z, lo2(wh1)); pkf(ah[r], q.w, hi2(wh1));
            }
        }
        #pragma unroll
        for (int r = 0; r < RPT; r++) {
            const float n0 = fmaf(zg[r].x, h1c[r].x, (1.0f - zg[r].x) * tanhf(ah[r].x));
            const float n1 = fmaf(zg[r].y, h1c[r].y, (1.0f - zg[r].y) * tanhf(ah[r].y));
            H1wrL[(iA + r) * HID + f0] = n0;          // LDS: for B's P3 (cross-wave)
            H1wrL[(iA + r) * HID + f1] = n1;
            H1wrG[(iA + r) * HID + f0] = n0;          // global: for own next P1
            H1wrG[(iA + r) * HID + f1] = n1;
            h1keep[r] = (v2f){n0, n1};
        }
    };

    // ======== pipeline prologue: A computes step 0 (reads zeroed buf 1) ======
    if (isA) layer1(0);
    __syncthreads();

    // ======== main ticks: A does step k+1, B does step k (ONE barrier) ======
    for (int k = 0; k < TSTEPS; k++) {
        if (isA) {
            if (k + 1 < TSTEPS) {
                layer1(k + 1);
                // sax prefetch for step k+2 (threads 0..23 = wave 0 = A)
                if (t < NROW && k + 2 < TSTEPS) {
                    const float* xt = xb + (size_t)(k + 2) * NN;
                    float a = 0.0f;
                    for (int j = 0; j < NN; j++) a = fmaf(sA[t * NN + j], xt[j], a);
                    sax[(k + 2) & 1][t] = a;
                }
            }
        } else {
            // ----- group B: step k -----
            const float* H1rd = sH1[k & 1];   // cross-wave, via LDS + barrier
            // P3: AH = A @ H1 (own rows) -> GLOBAL staging
            v2f aa[RPT];
            #pragma unroll
            for (int r = 0; r < RPT; r++) aa[r] = (v2f){0.0f, 0.0f};
            for (int j = 0; j < NN; j++) {
                const v2f hj = {H1rd[j * HID + f0], H1rd[j * HID + f1]};
                #pragma unroll
                for (int r = 0; r < RPT; r++) {
                    const float arj = sA[(iA + r) * NN + j];
                    aa[r] = __builtin_elementwise_fma((v2f){arj, arj}, hj, aa[r]);
                }
            }
            #pragma unroll
            for (int r = 0; r < RPT; r++) {
                ahgb[(iA + r) * HID + f0] = aa[r].x;
                ahgb[(iA + r) * HID + f1] = aa[r].y;
            }
            // P4: layer-2 gcn + z,r gates — AH and H2 broadcast from GLOBAL
            const float4* gAH = (const float4*)ahgb;   // store->load same ptr: compiler orders
            const float4* gH2 = (const float4*)h2gb;   // written last tick (barrier drained)
            v2f pz[RPT], pr[RPT], ph[RPT];
            #pragma unroll
            for (int r = 0; r < RPT; r++) { pz[r] = cz2v; pr[r] = cr2v; ph[r] = ch2v; }
            for (int c = 0; c < 32; ++c) {
                const float4 wz0 = We2[c * 384 + f0];
                const float4 wz1 = We2[c * 384 + 64 + f0];
                const float4 wr0 = We2[c * 384 + 128 + f0];
                const float4 wr1 = We2[c * 384 + 192 + f0];
                const float4 wh0 = We2[c * 384 + 256 + f0];
                const float4 wh1 = We2[c * 384 + 320 + f0];
                const float4 lz0 = Lzr2[c * 256 + f0];
                const float4 lz1 = Lzr2[c * 256 + 64 + f0];
                const float4 lr0 = Lzr2[c * 256 + 128 + f0];
                const float4 lr1 = Lzr2[c * 256 + 192 + f0];
                #pragma unroll
                for (int r = 0; r < RPT; r++) {
                    const float4 a = gAH[(iA + r) * 32 + c];
                    const float4 q = gH2[(iA + r) * 32 + c];
                    // a-chunk then q-chunk per c (rounds 4-9 order)
                    pkf(pz[r], a.x, lo2(wz0)); pkf(pz[r], a.y, hi2(wz0));
                    pkf(pz[r], a.z, lo2(wz1)); pkf(pz[r], a.w, hi2(wz1));
                    pkf(pz[r], q.x, lo2(lz0)); pkf(pz[r], q.y, hi2(lz0));
                    pkf(pz[r], q.z, lo2(lz1)); pkf(pz[r], q.w, hi2(lz1));
                    pkf(pr[r], a.x, lo2(wr0)); pkf(pr[r], a.y, hi2(wr0));
                    pkf(pr[r], a.z, lo2(wr1)); pkf(pr[r], a.w, hi2(wr1));
                    pkf(pr[r], q.x, lo2(lr0)); pkf(pr[r], q.y, hi2(lr0));
                    pkf(pr[r], q.z, lo2(lr1)); pkf(pr[r], q.w, hi2(lr1));
                    pkf(ph[r], a.x, lo2(wh0)); pkf(ph[r], a.y, hi2(wh0));
                    pkf(ph[r], a.z, lo2(wh1)); pkf(ph[r], a.w, hi2(wh1));
                }
            }
            v2f z2[RPT], h2c[RPT];
            #pragma unroll
            for (int r = 0; r < RPT; r++) {
                z2[r].x = sigmoidf(pz[r].x);
                z2[r].y = sigmoidf(pz[r].y);
                const float r20 = sigmoidf(pr[r].x);
                const float r21 = sigmoidf(pr[r].y);
                h2c[r] = h2keep[r];                   // own values, from regs
                sHR2[(iA + r) * HID + f0] = h2c[r].x * r20;
                sHR2[(iA + r) * HID + f1] = h2c[r].y * r21;
            }
            WAVE_SYNC();
            // P5: layer-2 h gate + H2 update + output accum — HR2 via LDS
            for (int c = 0; c < 32; ++c) {
                const float4 lh0 = Lh2[c * 128 + f0];
                const float4 lh1 = Lh2[c * 128 + 64 + f0];
                #pragma unroll
                for (int r = 0; r < RPT; r++) {
                    const float4 q = HR2v[(iA + r) * 32 + c];
                    pkf(ph[r], q.x, lo2(lh0)); pkf(ph[r], q.y, hi2(lh0));
                    pkf(ph[r], q.z, lo2(lh1)); pkf(ph[r], q.w, hi2(lh1));
                }
            }
            #pragma unroll
            for (int r = 0; r < RPT; r++) {
                const float m0 = fmaf(z2[r].x, h2c[r].x, (1.0f - z2[r].x) * tanhf(ph[r].x));
                const float m1 = fmaf(z2[r].y, h2c[r].y, (1.0f - z2[r].y) * tanhf(ph[r].y));
                h2gb[(iA + r) * HID + f0] = m0;       // global: for next tick's P4
                h2gb[(iA + r) * HID + f1] = m1;
                h2keep[r] = (v2f){m0, m1};
                if (r < nreal) {
                    oacc0 += (double)m0;
                    oacc1 += (double)m1;
                }
            }
        }
        __syncthreads();   // the ONE tick barrier (drains vmcnt: staging visible)
    }

    // ---------- Epilogue: mean over (T, nodes), dot with cls_w ----------
    if (!isA) {
        sred[gw][f0] = oacc0;
        sred[gw][f1] = oacc1;
    }
    __syncthreads();
    if (t < HID) {
        double s = 0.0;
        for (int gg = 0; gg < 4; gg++) s += sred[gg][t];
        sred[0][t] = (s / (double)(TSTEPS * NN)) * (double)cls_w[t];
    }
    __syncthreads();
    if (t < 64) {
        double v = ((double*)sred)[t] + ((double*)sred)[t + 64];
        for (int off = 32; off; off >>= 1) v += __shfl_down(v, off, 64);
        if (t == 0) out[b] = (float)(v + (double)cls_b[0]);
    }
}

extern "C" void kernel_launch(void* const* d_in, const int* in_sizes, int n_in,
                              void* d_out, int out_size, void* d_ws, size_t ws_size,
                              hipStream_t stream) {
    const float* x    = (const float*)d_in[0];
    const int*   ei   = (const int*)  d_in[1];
    const float* ew   = (const float*)d_in[2];
    const float* Wz1  = (const float*)d_in[3];
    const float* bz1  = (const float*)d_in[4];
    const float* lzw1 = (const float*)d_in[5];
    const float* lzb1 = (const float*)d_in[6];
    const float* Wr1  = (const float*)d_in[7];
    const float* br1  = (const float*)d_in[8];
    const float* lrw1 = (const float*)d_in[9];
    const float* lrb1 = (const float*)d_in[10];
    const float* Wh1  = (const float*)d_in[11];
    const float* bh1  = (const float*)d_in[12];
    const float* lhw1 = (const float*)d_in[13];
    const float* lhb1 = (const float*)d_in[14];
    const float* Wz2  = (const float*)d_in[15];
    const float* bz2  = (const float*)d_in[16];
    const float* lzw2 = (const float*)d_in[17];
    const float* lzb2 = (const float*)d_in[18];
    const float* Wr2  = (const float*)d_in[19];
    const float* br2  = (const float*)d_in[20];
    const float* lrw2 = (const float*)d_in[21];
    const float* lrb2 = (const float*)d_in[22];
    const float* Wh2  = (const float*)d_in[23];
    const float* bh2  = (const float*)d_in[24];
    const float* lhw2 = (const float*)d_in[25];
    const float* lhb2 = (const float*)d_in[26];
    const float* clsw = (const float*)d_in[27];
    const float* clsb = (const float*)d_in[28];

    float* ws   = (float*)d_ws;
    float* outp = (float*)d_out;

    build_A<<<1, 64, 0, stream>>>(ei, ew, ws + WS_A);
    pack_bot<<<32, 256, 0, stream>>>(lzw1, lrw1, (float4*)(ws + WS_LZR1), 2);
    pack_bot<<<16, 256, 0, stream>>>(lhw1, lhw1, (float4*)(ws + WS_LH1), 1);
    pack_bot<<<32, 256, 0, stream>>>(lzw2, lrw2, (float4*)(ws + WS_LZR2), 2);
    pack_bot<<<16, 256, 0, stream>>>(lhw2, lhw2, (float4*)(ws + WS_LH2), 1);
    make_weff2<<<48, 256, 0, stream>>>(Wz2, Wr2, Wh2, lzw2, lrw2, lhw2,
                                       (float4*)(ws + WS_WE2));
    make_vecs<<<5, 256, 0, stream>>>(Wz1, Wr1, Wh1, bz1, br1, bh1,
                                     lzw1, lrw1, lhw1, lzb1, lrb1, lhb1,
                                     bz2, br2, bh2, lzw2, lrw2, lhw2,
                                     lzb2, lrb2, lhb2, ws + WS_VEC);
    tgcn_main<<<64, NTHREADS, 0, stream>>>(x, ws,
                                           ws + WS_H1G, ws + WS_AHG, ws + WS_H2G,
                                           clsw, clsb, outp);
}

// Round 11
// 12761.476 us; speedup vs baseline: 1.7094x; 1.7094x over previous
//
#include <hip/hip_runtime.h>
#include <hip/hip_bf16.h>

// TGCN: B=64, T=500, N=21, HID=128.
// Round 11 = round 7 champion (12.5 ms) + exact waste removal:
//  (a) compile-time row specialization: wave gw==3 of each group runs an R=3
//      instantiation (rows 18-20 only) instead of computing 3 pad rows —
//      removes 12.5% of LDS broadcast reads / FMA / transcendentals with
//      ZERO change to any real-row accumulation chain (pad rows never feed
//      real outputs: P3 j<21, oacc excluded pads already).
//  (b) sax x-loads hoisted above layer1 (same ops, earlier issue).
// Structure: 8 waves (4 A = layer1 step k+1, 4 B = layer2 step k), ONE
// barrier per tick, pk-packed column pairs (f0,f0+64). Accumulation chains
// BIT-IDENTICAL to rounds 4-7. Never reorder fp32 sums in the recurrence.

#define NN 21
#define NROW 24            // padded rows (buffers only; pads never computed)
#define HID 128
#define TSTEPS 500
#define EDGES 210
#define NTHREADS 512       // 8 waves: 4 per group

// ws layout (float offsets)
#define WS_A     0        // NROW*NN floats (pad rows zeroed on build)
#define WS_VEC   1600     // 9*128
#define WS_LZR1  3200     // 32*256*4 floats
#define WS_LH1   36000    // 32*128*4
#define WS_WE2   52400    // 32*384*4
#define WS_LZR2  101600   // 32*256*4
#define WS_LH2   134400   // 32*128*4

#define WAVE_SYNC() asm volatile("s_waitcnt lgkmcnt(0)" ::: "memory")

template <int N> struct IC { static constexpr int value = N; };

typedef float v2f __attribute__((ext_vector_type(2)));

__device__ __forceinline__ v2f lo2(float4 w) { v2f v = {w.x, w.y}; return v; }
__device__ __forceinline__ v2f hi2(float4 w) { v2f v = {w.z, w.w}; return v; }
__device__ __forceinline__ void pkf(v2f& acc, float s, v2f w) {
    v2f ss = {s, s};
    acc = __builtin_elementwise_fma(ss, w, acc);
}
__device__ __forceinline__ float sigmoidf(float v) {
    return 1.0f / (1.0f + expf(-v));
}

// ---- Prologue: build normalized adjacency A (21x21) in fp64, store fp32 ----
__global__ void build_A(const int* __restrict__ ei, const float* __restrict__ ew,
                        float* __restrict__ Aout) {
    __shared__ double deg[NN];
    __shared__ double dinv[NN];
    __shared__ double Asm[NN * NN];
    int t = threadIdx.x;
    for (int k = t; k < NN * NN; k += blockDim.x) Asm[k] = 0.0;
    if (t < NN) deg[t] = 1.0;  // self loop weight 1
    __syncthreads();
    if (t == 0) {
        for (int e = 0; e < EDGES; e++) deg[ei[EDGES + e]] += (double)ew[e];
        for (int i = 0; i < NN; i++) dinv[i] = deg[i] > 0.0 ? 1.0 / sqrt(deg[i]) : 0.0;
        for (int e = 0; e < EDGES; e++) {
            int s = ei[e], d = ei[EDGES + e];
            Asm[d * NN + s] += dinv[s] * (double)ew[e] * dinv[d];
        }
        for (int i = 0; i < NN; i++) Asm[i * NN + i] += dinv[i] * dinv[i];
    }
    __syncthreads();
    for (int k = t; k < NROW * NN; k += blockDim.x)
        Aout[k] = (k < NN * NN) ? (float)Asm[k] : 0.0f;
}

// ---- Prologue: repack bottom halves of (256,128) concat weights ----------
// Pair-interleaved: float4 idx = c*(ngate*128) + gate*128 + k2*64 + f0,
// k = 4c + 2*k2, contents {w[k][f0], w[k][f0+64], w[k+1][f0], w[k+1][f0+64]}
__global__ void pack_bot(const float* __restrict__ w0, const float* __restrict__ w1,
                         float4* __restrict__ out, int ngate) {
    int t = blockIdx.x * blockDim.x + threadIdx.x;
    int per_c = ngate * 128;
    int total = 32 * per_c;
    if (t >= total) return;
    int c = t / per_c, rem = t - c * per_c;
    int gate = rem >> 7;
    int r2 = rem & 127;
    int k2 = r2 >> 6;
    int f0 = r2 & 63;
    int k = 4 * c + 2 * k2;
    const float* src = (gate == 0) ? w0 : w1;
    float4 v;
    v.x = src[(128 + k) * 128 + f0];
    v.y = src[(128 + k) * 128 + f0 + 64];
    v.z = src[(128 + k + 1) * 128 + f0];
    v.w = src[(128 + k + 1) * 128 + f0 + 64];
    out[t] = v;
}

// ---- Prologue: Weff2_g = Wg_2 @ lgw_2_top, pair-interleaved, fp64 accum ----
__global__ void make_weff2(const float* __restrict__ Wz2, const float* __restrict__ Wr2,
                           const float* __restrict__ Wh2,
                           const float* __restrict__ lzw2, const float* __restrict__ lrw2,
                           const float* __restrict__ lhw2,
                           float4* __restrict__ out) {
    int t = blockIdx.x * blockDim.x + threadIdx.x;  // [0, 32*384)
    if (t >= 32 * 384) return;
    int c = t / 384, rem = t - c * 384;
    int g = rem >> 7;
    int r2 = rem & 127;
    int k2 = r2 >> 6;
    int f0 = r2 & 63;
    int k = 4 * c + 2 * k2;
    const float* W = (g == 0) ? Wz2 : (g == 1) ? Wr2 : Wh2;
    const float* L = (g == 0) ? lzw2 : (g == 1) ? lrw2 : lhw2;
    double a0 = 0, a1 = 0, a2 = 0, a3 = 0;
    for (int m = 0; m < 128; m++) {
        double w0 = (double)W[k * 128 + m];
        double w1 = (double)W[(k + 1) * 128 + m];
        a0 += w0 * (double)L[m * 128 + f0];
        a1 += w0 * (double)L[m * 128 + f0 + 64];
        a2 += w1 * (double)L[m * 128 + f0];
        a3 += w1 * (double)L[m * 128 + f0 + 64];
    }
    out[t] = make_float4((float)a0, (float)a1, (float)a2, (float)a3);
}

// ---- Prologue: layer-1 effective row vectors + all bias consts (fp64) ----
__global__ void make_vecs(const float* __restrict__ Wz1, const float* __restrict__ Wr1,
                          const float* __restrict__ Wh1,
                          const float* __restrict__ bz1, const float* __restrict__ br1,
                          const float* __restrict__ bh1,
                          const float* __restrict__ lzw1, const float* __restrict__ lrw1,
                          const float* __restrict__ lhw1,
                          const float* __restrict__ lzb1, const float* __restrict__ lrb1,
                          const float* __restrict__ lhb1,
                          const float* __restrict__ bz2, const float* __restrict__ br2,
                          const float* __restrict__ bh2,
                          const float* __restrict__ lzw2, const float* __restrict__ lrw2,
                          const float* __restrict__ lhw2,
                          const float* __restrict__ lzb2, const float* __restrict__ lrb2,
                          const float* __restrict__ lhb2,
                          float* __restrict__ out) {
    int t = blockIdx.x * blockDim.x + threadIdx.x;
    if (t >= 9 * 128) return;
    int v = t >> 7, f = t & 127;
    double acc = 0.0;
    if (v < 3) {
        const float* W = (v == 0) ? Wz1 : (v == 1) ? Wr1 : Wh1;   // (1,128)
        const float* L = (v == 0) ? lzw1 : (v == 1) ? lrw1 : lhw1;
        for (int m = 0; m < 128; m++) acc += (double)W[m] * (double)L[m * 128 + f];
    } else if (v < 6) {
        int g = v - 3;
        const float* bb = (g == 0) ? bz1 : (g == 1) ? br1 : bh1;
        const float* L  = (g == 0) ? lzw1 : (g == 1) ? lrw1 : lhw1;
        const float* lb = (g == 0) ? lzb1 : (g == 1) ? lrb1 : lhb1;
        for (int m = 0; m < 128; m++) acc += (double)bb[m] * (double)L[m * 128 + f];
        acc += (double)lb[f];
    } else {
        int g = v - 6;
        const float* bb = (g == 0) ? bz2 : (g == 1) ? br2 : bh2;
        const float* L  = (g == 0) ? lzw2 : (g == 1) ? lrw2 : lhw2;
        const float* lb = (g == 0) ? lzb2 : (g == 1) ? lrb2 : lhb2;
        for (int m = 0; m < 128; m++) acc += (double)bb[m] * (double)L[m * 128 + f];
        acc += (double)lb[f];
    }
    out[t] = (float)acc;
}

// ---- Main: one block per batch, layer-pipelined groups, 1 barrier/tick ----
__global__ __launch_bounds__(NTHREADS, 2) void tgcn_main(
    const float* __restrict__ x,       // (64,500,21)
    const float* __restrict__ ws,
    const float* __restrict__ cls_w,   // (128,1)
    const float* __restrict__ cls_b,   // (1,)
    float* __restrict__ out)           // (64,)
{
    const int b  = blockIdx.x;
    const int t  = threadIdx.x;
    const bool isA = (t < 256);                              // wave-uniform
    const int lt = t & 255;
    const int f0 = lt & 63;
    const int f1 = f0 + 64;
    const int gw = __builtin_amdgcn_readfirstlane(lt >> 6);  // 0..3 in group
    const int iA = gw * 6;

    __shared__ __align__(16) float sH1[2][NROW * HID];  // double-buffered
    __shared__ __align__(16) float sH2[NROW * HID];
    __shared__ __align__(16) float sHR1[NROW * HID];
    __shared__ __align__(16) float sHR2[NROW * HID];
    __shared__ __align__(16) float sAH[NROW * HID];     // B-private, per tick
    __shared__ float sA[NROW * NN];
    __shared__ float sax[2][NROW];
    __shared__ double sred[4][HID];

    const float*  vecs = ws + WS_VEC;
    const float4* Lzr1 = (const float4*)(ws + WS_LZR1);
    const float4* Lh1  = (const float4*)(ws + WS_LH1);
    const float4* We2  = (const float4*)(ws + WS_WE2);
    const float4* Lzr2 = (const float4*)(ws + WS_LZR2);
    const float4* Lh2  = (const float4*)(ws + WS_LH2);

    const float4* H2v  = (const float4*)sH2;
    const float4* HR1v = (const float4*)sHR1;
    const float4* HR2v = (const float4*)sHR2;
    const float4* AHv  = (const float4*)sAH;

    for (int k = t; k < 2 * NROW * HID; k += NTHREADS) ((float*)sH1)[k] = 0.0f;
    for (int k = t; k < NROW * HID; k += NTHREADS) sH2[k] = 0.0f;
    for (int k = t; k < NROW * NN; k += NTHREADS) sA[k] = ws[WS_A + k];

    // per-column-pair constants
    const v2f wz1v = {vecs[f0],        vecs[f1]};
    const v2f wr1v = {vecs[128 + f0],  vecs[128 + f1]};
    const v2f wh1v = {vecs[256 + f0],  vecs[256 + f1]};
    const v2f cz1v = {vecs[384 + f0],  vecs[384 + f1]};
    const v2f cr1v = {vecs[512 + f0],  vecs[512 + f1]};
    const v2f ch1v = {vecs[640 + f0],  vecs[640 + f1]};
    const v2f cz2v = {vecs[768 + f0],  vecs[768 + f1]};
    const v2f cr2v = {vecs[896 + f0],  vecs[896 + f1]};
    const v2f ch2v = {vecs[1024 + f0], vecs[1024 + f1]};

    __syncthreads();

    const float* xb = x + (size_t)b * (TSTEPS * NN);
    if (t < NROW) {  // sax for steps 0 and 1 (slot = s&1)
        float a0s = 0.0f, a1s = 0.0f;
        for (int j = 0; j < NN; j++) {
            a0s = fmaf(sA[t * NN + j], xb[j], a0s);
            a1s = fmaf(sA[t * NN + j], xb[NN + j], a1s);
        }
        sax[0][t] = a0s;
        sax[1][t] = a1s;
    }
    __syncthreads();

    double oacc0 = 0.0, oacc1 = 0.0;   // group B only

    // ============ A-group layer-1 body, R = compile-time rows (6 or 3) =======
    auto layer1 = [&](auto rc, int s) {
        constexpr int R = decltype(rc)::value;
        const float* H1rd = sH1[(s + 1) & 1];   // state after step s-1
        float*       H1wr = sH1[s & 1];
        const float4* H1c = (const float4*)H1rd;
        float axp[R];
        #pragma unroll
        for (int r = 0; r < R; r++) axp[r] = sax[s & 1][iA + r];
        // P1: z,r gates
        v2f az[R], ar[R];
        #pragma unroll
        for (int r = 0; r < R; r++) {
            az[r] = __builtin_elementwise_fma((v2f){axp[r], axp[r]}, wz1v, cz1v);
            ar[r] = __builtin_elementwise_fma((v2f){axp[r], axp[r]}, wr1v, cr1v);
        }
        for (int c = 0; c < 32; ++c) {
            const float4 wz0 = Lzr1[c * 256 + f0];
            const float4 wz1 = Lzr1[c * 256 + 64 + f0];
            const float4 wr0 = Lzr1[c * 256 + 128 + f0];
            const float4 wr1 = Lzr1[c * 256 + 192 + f0];
            #pragma unroll
            for (int r = 0; r < R; r++) {
                const float4 h = H1c[(iA + r) * 32 + c];
                pkf(az[r], h.x, lo2(wz0)); pkf(az[r], h.y, hi2(wz0));
                pkf(az[r], h.z, lo2(wz1)); pkf(az[r], h.w, hi2(wz1));
                pkf(ar[r], h.x, lo2(wr0)); pkf(ar[r], h.y, hi2(wr0));
                pkf(ar[r], h.z, lo2(wr1)); pkf(ar[r], h.w, hi2(wr1));
            }
        }
        v2f zg[R], h1c[R];
        #pragma unroll
        for (int r = 0; r < R; r++) {
            zg[r].x = sigmoidf(az[r].x);
            zg[r].y = sigmoidf(az[r].y);
            const float r0 = sigmoidf(ar[r].x);
            const float r1 = sigmoidf(ar[r].y);
            h1c[r].x = H1rd[(iA + r) * HID + f0];
            h1c[r].y = H1rd[(iA + r) * HID + f1];
            sHR1[(iA + r) * HID + f0] = h1c[r].x * r0;
            sHR1[(iA + r) * HID + f1] = h1c[r].y * r1;
        }
        WAVE_SYNC();
        // P2: h gate + H1 update
        v2f ah[R];
        #pragma unroll
        for (int r = 0; r < R; r++)
            ah[r] = __builtin_elementwise_fma((v2f){axp[r], axp[r]}, wh1v, ch1v);
        for (int c = 0; c < 32; ++c) {
            const float4 wh0 = Lh1[c * 128 + f0];
            const float4 wh1 = Lh1[c * 128 + 64 + f0];
            #pragma unroll
            for (int r = 0; r < R; r++) {
                const float4 q = HR1v[(iA + r) * 32 + c];
                pkf(ah[r], q.x, lo2(wh0)); pkf(ah[r], q.y, hi2(wh0));
                pkf(ah[r], q.z, lo2(wh1)); pkf(ah[r], q.w, hi2(wh1));
            }
        }
        #pragma unroll
        for (int r = 0; r < R; r++) {
            const float n0 = fmaf(zg[r].x, h1c[r].x, (1.0f - zg[r].x) * tanhf(ah[r].x));
            const float n1 = fmaf(zg[r].y, h1c[r].y, (1.0f - zg[r].y) * tanhf(ah[r].y));
            H1wr[(iA + r) * HID + f0] = n0;
            H1wr[(iA + r) * HID + f1] = n1;
        }
    };

    // ============ B-group layer-2 body, R = compile-time rows (6 or 3) =======
    auto layer2 = [&](auto rc, int k) {
        constexpr int R = decltype(rc)::value;
        const float* H1rd = sH1[k & 1];   // state after step k
        // P3: AH = A @ H1 (own rows; all H1 rows published at barrier)
        v2f aa[R];
        #pragma unroll
        for (int r = 0; r < R; r++) aa[r] = (v2f){0.0f, 0.0f};
        #pragma unroll 3
        for (int j = 0; j < NN; j++) {
            const v2f hj = {H1rd[j * HID + f0], H1rd[j * HID + f1]};
            #pragma unroll
            for (int r = 0; r < R; r++) {
                const float arj = sA[(iA + r) * NN + j];
                aa[r] = __builtin_elementwise_fma((v2f){arj, arj}, hj, aa[r]);
            }
        }
        #pragma unroll
        for (int r = 0; r < R; r++) {
            sAH[(iA + r) * HID + f0] = aa[r].x;
            sAH[(iA + r) * HID + f1] = aa[r].y;
        }
        WAVE_SYNC();
        // P4: layer-2 gcn + z,r gates
        v2f pz[R], pr[R], ph[R];
        #pragma unroll
        for (int r = 0; r < R; r++) { pz[r] = cz2v; pr[r] = cr2v; ph[r] = ch2v; }
        for (int c = 0; c < 32; ++c) {
            const float4 wz0 = We2[c * 384 + f0];
            const float4 wz1 = We2[c * 384 + 64 + f0];
            const float4 wr0 = We2[c * 384 + 128 + f0];
            const float4 wr1 = We2[c * 384 + 192 + f0];
            const float4 wh0 = We2[c * 384 + 256 + f0];
            const float4 wh1 = We2[c * 384 + 320 + f0];
            const float4 lz0 = Lzr2[c * 256 + f0];
            const float4 lz1 = Lzr2[c * 256 + 64 + f0];
            const float4 lr0 = Lzr2[c * 256 + 128 + f0];
            const float4 lr1 = Lzr2[c * 256 + 192 + f0];
            #pragma unroll
            for (int r = 0; r < R; r++) {
                const float4 a = AHv[(iA + r) * 32 + c];
                const float4 q = H2v[(iA + r) * 32 + c];
                // a-chunk then q-chunk per c (rounds 4-7 order)
                pkf(pz[r], a.x, lo2(wz0)); pkf(pz[r], a.y, hi2(wz0));
                pkf(pz[r], a.z, lo2(wz1)); pkf(pz[r], a.w, hi2(wz1));
                pkf(pz[r], q.x, lo2(lz0)); pkf(pz[r], q.y, hi2(lz0));
                pkf(pz[r], q.z, lo2(lz1)); pkf(pz[r], q.w, hi2(lz1));
                pkf(pr[r], a.x, lo2(wr0)); pkf(pr[r], a.y, hi2(wr0));
                pkf(pr[r], a.z, lo2(wr1)); pkf(pr[r], a.w, hi2(wr1));
                pkf(pr[r], q.x, lo2(lr0)); pkf(pr[r], q.y, hi2(lr0));
                pkf(pr[r], q.z, lo2(lr1)); pkf(pr[r], q.w, hi2(lr1));
                pkf(ph[r], a.x, lo2(wh0)); pkf(ph[r], a.y, hi2(wh0));
                pkf(ph[r], a.z, lo2(wh1)); pkf(ph[r], a.w, hi2(wh1));
            }
        }
        v2f z2[R], h2c[R];
        #pragma unroll
        for (int r = 0; r < R; r++) {
            z2[r].x = sigmoidf(pz[r].x);
            z2[r].y = sigmoidf(pz[r].y);
            const float r20 = sigmoidf(pr[r].x);
            const float r21 = sigmoidf(pr[r].y);
            h2c[r].x = sH2[(iA + r) * HID + f0];
            h2c[r].y = sH2[(iA + r) * HID + f1];
            sHR2[(iA + r) * HID + f0] = h2c[r].x * r20;
            sHR2[(iA + r) * HID + f1] = h2c[r].y * r21;
        }
        WAVE_SYNC();
        // P5: layer-2 h gate + H2 update + output accum
        for (int c = 0; c < 32; ++c) {
            const float4 lh0 = Lh2[c * 128 + f0];
            const float4 lh1 = Lh2[c * 128 + 64 + f0];
            #pragma unroll
            for (int r = 0; r < R; r++) {
                const float4 q = HR2v[(iA + r) * 32 + c];
                pkf(ph[r], q.x, lo2(lh0)); pkf(ph[r], q.y, hi2(lh0));
                pkf(ph[r], q.z, lo2(lh1)); pkf(ph[r], q.w, hi2(lh1));
            }
        }
        #pragma unroll
        for (int r = 0; r < R; r++) {
            const float m0 = fmaf(z2[r].x, h2c[r].x, (1.0f - z2[r].x) * tanhf(ph[r].x));
            const float m1 = fmaf(z2[r].y, h2c[r].y, (1.0f - z2[r].y) * tanhf(ph[r].y));
            sH2[(iA + r) * HID + f0] = m0;
            sH2[(iA + r) * HID + f1] = m1;
            oacc0 += (double)m0;    // all R rows are real rows
            oacc1 += (double)m1;
        }
    };

    // ======== pipeline prologue: A computes step 0 (reads zeroed buf 1) ======
    if (isA) {
        if (gw == 3) layer1(IC<3>{}, 0); else layer1(IC<6>{}, 0);
    }
    __syncthreads();

    // ======== main ticks: A does step k+1, B does step k (ONE barrier) ======
    for (int k = 0; k < TSTEPS; k++) {
        if (isA) {
            if (k + 1 < TSTEPS) {
                // hoisted x loads for sax(k+2): issue global loads early
                float xv[NN];
                const bool doPre = (t < NROW) && (k + 2 < TSTEPS);
                if (doPre) {
                    const float* xt = xb + (size_t)(k + 2) * NN;
                    #pragma unroll
                    for (int j = 0; j < NN; j++) xv[j] = xt[j];
                }
                if (gw == 3) layer1(IC<3>{}, k + 1); else layer1(IC<6>{}, k + 1);
                if (doPre) {
                    float a = 0.0f;
                    for (int j = 0; j < NN; j++) a = fmaf(sA[t * NN + j], xv[j], a);
                    sax[(k + 2) & 1][t] = a;
                }
            }
        } else {
            if (gw == 3) layer2(IC<3>{}, k); else layer2(IC<6>{}, k);
        }
        __syncthreads();   // the ONE tick barrier: publishes H1(k+1), sax(k+2)
    }

    // ---------- Epilogue: mean over (T, nodes), dot with cls_w ----------
    if (!isA) {
        sred[gw][f0] = oacc0;
        sred[gw][f1] = oacc1;
    }
    __syncthreads();
    if (t < HID) {
        double s = 0.0;
        for (int gg = 0; gg < 4; gg++) s += sred[gg][t];
        sred[0][t] = (s / (double)(TSTEPS * NN)) * (double)cls_w[t];
    }
    __syncthreads();
    if (t < 64) {
        double v = ((double*)sred)[t] + ((double*)sred)[t + 64];
        for (int off = 32; off; off >>= 1) v += __shfl_down(v, off, 64);
        if (t == 0) out[b] = (float)(v + (double)cls_b[0]);
    }
}

extern "C" void kernel_launch(void* const* d_in, const int* in_sizes, int n_in,
                              void* d_out, int out_size, void* d_ws, size_t ws_size,
                              hipStream_t stream) {
    const float* x    = (const float*)d_in[0];
    const int*   ei   = (const int*)  d_in[1];
    const float* ew   = (const float*)d_in[2];
    const float* Wz1  = (const float*)d_in[3];
    const float* bz1  = (const float*)d_in[4];
    const float* lzw1 = (const float*)d_in[5];
    const float* lzb1 = (const float*)d_in[6];
    const float* Wr1  = (const float*)d_in[7];
    const float* br1  = (const float*)d_in[8];
    const float* lrw1 = (const float*)d_in[9];
    const float* lrb1 = (const float*)d_in[10];
    const float* Wh1  = (const float*)d_in[11];
    const float* bh1  = (const float*)d_in[12];
    const float* lhw1 = (const float*)d_in[13];
    const float* lhb1 = (const float*)d_in[14];
    const float* Wz2  = (const float*)d_in[15];
    const float* bz2  = (const float*)d_in[16];
    const float* lzw2 = (const float*)d_in[17];
    const float* lzb2 = (const float*)d_in[18];
    const float* Wr2  = (const float*)d_in[19];
    const float* br2  = (const float*)d_in[20];
    const float* lrw2 = (const float*)d_in[21];
    const float* lrb2 = (const float*)d_in[22];
    const float* Wh2  = (const float*)d_in[23];
    const float* bh2  = (const float*)d_in[24];
    const float* lhw2 = (const float*)d_in[25];
    const float* lhb2 = (const float*)d_in[26];
    const float* clsw = (const float*)d_in[27];
    const float* clsb = (const float*)d_in[28];

    float* ws   = (float*)d_ws;
    float* outp = (float*)d_out;

    build_A<<<1, 64, 0, stream>>>(ei, ew, ws + WS_A);
    pack_bot<<<32, 256, 0, stream>>>(lzw1, lrw1, (float4*)(ws + WS_LZR1), 2);
    pack_bot<<<16, 256, 0, stream>>>(lhw1, lhw1, (float4*)(ws + WS_LH1), 1);
    pack_bot<<<32, 256, 0, stream>>>(lzw2, lrw2, (float4*)(ws + WS_LZR2), 2);
    pack_bot<<<16, 256, 0, stream>>>(lhw2, lhw2, (float4*)(ws + WS_LH2), 1);
    make_weff2<<<48, 256, 0, stream>>>(Wz2, Wr2, Wh2, lzw2, lrw2, lhw2,
                                       (float4*)(ws + WS_WE2));
    make_vecs<<<5, 256, 0, stream>>>(Wz1, Wr1, Wh1, bz1, br1, bh1,
                                     lzw1, lrw1, lhw1, lzb1, lrb1, lhb1,
                                     bz2, br2, bh2, lzw2, lrw2, lhw2,
                                     lzb2, lrb2, lhb2, ws + WS_VEC);
    tgcn_main<<<64, NTHREADS, 0, stream>>>(x, ws, clsw, clsb, outp);
}